// Round 8
// baseline (1050.873 us; speedup 1.0000x reference)
//
#include <hip/hip_runtime.h>
#include <math.h>

#define NPTS 4096
#define LOGN 8.317766166719343f   // log(4096)
#define LN2f 0.6931471805599453f
#define LOG2E 1.4426950408889634f

#define NSTEPS 11
#define JSPLIT 4
#define JCHUNK (NPTS / JSPLIT)            // 1024 columns per block
#define RPW 8                             // rows per wave
#define RPB 32                            // rows per block (4 waves)
#define NRBLK (NPTS / RPB)                // 128
#define BPP (NRBLK * JSPLIT)              // 512 blocks per problem; grid = 1536 (6/CU)

typedef float f2 __attribute__((ext_vector_type(2)));
static __device__ __forceinline__ f2 mk2(float a, float b) { f2 r; r.x = a; r.y = b; return r; }

// ws layout:
//   float2 pa[2*NPTS]   : (x,y)  per cloud (0=x-cloud, 1=y-cloud)
//   float2 pb[2*NPTS]   : (z,|p|^2) per cloud
//   float2 part[24*NPTS]: (m,s) partial; index ((prob*2+side)*JSPLIT + js)*NPTS + row
#define PA_F2(ws)   ((float2*)(ws))
#define PB_F2(ws)   ((float2*)((ws) + 4 * NPTS))
#define PART_F2(ws) ((float2*)((ws) + 8 * NPTS))

__global__ void prep_kernel(const float* __restrict__ x, const float* __restrict__ y,
                            float* __restrict__ ws) {
    int j = blockIdx.x * 256 + threadIdx.x;
    if (j >= NPTS) return;
    float2* pa = PA_F2(ws); float2* pb = PB_F2(ws); float2* part = PART_F2(ws);
    float ax = x[3*j], ay = x[3*j+1], az = x[3*j+2];
    pa[j] = make_float2(ax, ay);
    pb[j] = make_float2(az, ax*ax + ay*ay + az*az);
    float bx = y[3*j], by = y[3*j+1], bz = y[3*j+2];
    pa[NPTS + j] = make_float2(bx, by);
    pb[NPTS + j] = make_float2(bz, bx*bx + by*by + bz*bz);
    // init partials so decoded dual == 0 at any eps: lse2 = 12 = log2(4096)
    #pragma unroll
    for (int ps = 0; ps < 6; ++ps) {
        #pragma unroll
        for (int p = 0; p < JSPLIT; ++p)
            part[(ps*JSPLIT + p) * NPTS + j] =
                (p == 0) ? make_float2(12.0f, 1.0f) : make_float2(0.0f, 0.0f);
    }
}

// One Sinkhorn half-update, online chunked-max, hw exp2 (R4 inner loop).
__global__ void __launch_bounds__(256, 6) sinkhorn_step(float* __restrict__ ws,
        float eps, float eps_dec, int half) {
    const float2* pa = PA_F2(ws);
    const float2* pb = PB_F2(ws);
    float2* part = PART_F2(ws);

    int bid = blockIdx.x;
    int prob = bid / BPP;                 // 0: xy, 1: xx, 2: yy
    int rem  = bid % BPP;
    int js   = rem & (JSPLIT - 1);
    int rblk = rem / JSPLIT;

    int rc, cc, in_side, out_side;
    if (half == 0) { rc = (prob == 2) ? 1 : 0; cc = (prob == 1) ? 0 : 1; in_side = 1; out_side = 0; }
    else           { rc = (prob == 1) ? 0 : 1; cc = (prob == 2) ? 1 : 0; in_side = 0; out_side = 1; }

    const float k = LOG2E / eps;          // base-2 log scale
    const float nhk = -0.5f * k;
    const int jbase = js * JCHUNK;

    __shared__ float bxL[JCHUNK], byL[JCHUNK], bzL[JCHUNK], uL[JCHUNK];  // 16 KB

    // ---- stage cols + decode input duals (4-way partial merge) ----
    {
        const float2* part_in = part + (prob*2 + in_side) * JSPLIT * NPTS;
        for (int i = threadIdx.x; i < JCHUNK; i += 256) {
            int j = jbase + i;
            float2 P0 = part_in[j];
            float2 P1 = part_in[NPTS + j];
            float2 P2 = part_in[2*NPTS + j];
            float2 P3 = part_in[3*NPTS + j];
            float M = fmaxf(fmaxf(P0.x, P1.x), fmaxf(P2.x, P3.x));
            float ssum = P0.y * __builtin_amdgcn_exp2f(P0.x - M)
                       + P1.y * __builtin_amdgcn_exp2f(P1.x - M)
                       + P2.y * __builtin_amdgcn_exp2f(P2.x - M)
                       + P3.y * __builtin_amdgcn_exp2f(P3.x - M);
            float lse2 = M + __builtin_amdgcn_logf(ssum);
            float g = -eps_dec * fmaf(LN2f, lse2, -LOGN);
            float2 A = pa[cc*NPTS + j];
            float2 B = pb[cc*NPTS + j];
            bxL[i] = A.x; byL[i] = A.y; bzL[i] = B.x;
            uL[i] = fmaf(B.y, nhk, g * k);
        }
    }
    __syncthreads();

    int wave = threadIdx.x >> 6;
    int lane = threadIdx.x & 63;
    int r0 = rblk * RPB + wave * RPW;

    float2* part_out = part + ((prob*2 + out_side) * JSPLIT + js) * NPTS;

    f2 AX[RPW], AY[RPW], AZ[RPW];
    float rak[RPW], m[RPW], s[RPW];
    #pragma unroll
    for (int r = 0; r < RPW; ++r) {
        float2 RA = pa[rc*NPTS + r0 + r];
        float2 RB = pb[rc*NPTS + r0 + r];
        float ax = RA.x * k, ay = RA.y * k, az = RB.x * k;
        AX[r] = mk2(ax, ax); AY[r] = mk2(ay, ay); AZ[r] = mk2(az, az);
        rak[r] = nhk * RB.y;
        m[r] = -INFINITY; s[r] = 0.0f;
    }

    // ---- main loop: 8 j's/lane/superiter (4 adjacent pairs), chunk max, 1 rescale ----
    for (int su = 0; su < JCHUNK / 512; ++su) {   // 2 superiters
        int c0 = su * 512 + 2 * lane;
        f2 BX[4], BY[4], BZ[4], U[4];
        #pragma unroll
        for (int p = 0; p < 4; ++p) {
            int j0 = c0 + p * 128;
            BX[p] = *(const f2*)&bxL[j0];
            BY[p] = *(const f2*)&byL[j0];
            BZ[p] = *(const f2*)&bzL[j0];
            U[p]  = *(const f2*)&uL[j0];
        }
        #pragma unroll
        for (int r = 0; r < RPW; ++r) {
            f2 t0 = __builtin_elementwise_fma(AX[r], BX[0],
                     __builtin_elementwise_fma(AY[r], BY[0],
                      __builtin_elementwise_fma(AZ[r], BZ[0], U[0])));
            f2 t1 = __builtin_elementwise_fma(AX[r], BX[1],
                     __builtin_elementwise_fma(AY[r], BY[1],
                      __builtin_elementwise_fma(AZ[r], BZ[1], U[1])));
            f2 t2 = __builtin_elementwise_fma(AX[r], BX[2],
                     __builtin_elementwise_fma(AY[r], BY[2],
                      __builtin_elementwise_fma(AZ[r], BZ[2], U[2])));
            f2 t3 = __builtin_elementwise_fma(AX[r], BX[3],
                     __builtin_elementwise_fma(AY[r], BY[3],
                      __builtin_elementwise_fma(AZ[r], BZ[3], U[3])));
            f2 q = __builtin_elementwise_max(
                     __builtin_elementwise_max(t0, t1),
                     __builtin_elementwise_max(t2, t3));
            float mn = fmaxf(fmaxf(q.x, q.y), m[r]);       // v_max3
            float er = __builtin_amdgcn_exp2f(m[r] - mn);  // 1 rescale per chunk of 8
            f2 mn2 = mk2(mn, mn);
            f2 d0 = t0 - mn2, d1 = t1 - mn2, d2 = t2 - mn2, d3 = t3 - mn2;
            f2 e0, e1, e2, e3;
            e0.x = __builtin_amdgcn_exp2f(d0.x); e0.y = __builtin_amdgcn_exp2f(d0.y);
            e1.x = __builtin_amdgcn_exp2f(d1.x); e1.y = __builtin_amdgcn_exp2f(d1.y);
            e2.x = __builtin_amdgcn_exp2f(d2.x); e2.y = __builtin_amdgcn_exp2f(d2.y);
            e3.x = __builtin_amdgcn_exp2f(d3.x); e3.y = __builtin_amdgcn_exp2f(d3.y);
            f2 acc = (e0 + e1) + (e2 + e3);
            s[r] = fmaf(s[r], er, acc.x + acc.y);
            m[r] = mn;
        }
    }

    // ---- wave reduce: max butterfly, one rescale, sum butterfly; write partial ----
    #pragma unroll
    for (int r = 0; r < RPW; ++r) {
        float M = m[r];
        for (int off = 32; off; off >>= 1) M = fmaxf(M, __shfl_xor(M, off));
        float ss = s[r] * __builtin_amdgcn_exp2f(m[r] - M);
        for (int off = 32; off; off >>= 1) ss += __shfl_xor(ss, off);
        if (lane == 0) part_out[r0 + r] = make_float2(M + rak[r], ss);
    }
}

__global__ void finalize_kernel(const float* __restrict__ ws, float* __restrict__ out,
                                float eps) {
    const float2* part = PART_F2((float*)ws);
    int tid = threadIdx.x;
    double acc = 0.0;
    for (int idx = tid; idx < 6 * NPTS; idx += 256) {
        int ps = idx >> 12;            // prob*2+side
        int row = idx & (NPTS - 1);
        const float2* pb_ = part + ps * JSPLIT * NPTS + row;
        float2 P0 = pb_[0];
        float2 P1 = pb_[NPTS];
        float2 P2 = pb_[2*NPTS];
        float2 P3 = pb_[3*NPTS];
        float M = fmaxf(fmaxf(P0.x, P1.x), fmaxf(P2.x, P3.x));
        float ssum = P0.y * __builtin_amdgcn_exp2f(P0.x - M)
                   + P1.y * __builtin_amdgcn_exp2f(P1.x - M)
                   + P2.y * __builtin_amdgcn_exp2f(P2.x - M)
                   + P3.y * __builtin_amdgcn_exp2f(P3.x - M);
        float lse2 = M + __builtin_amdgcn_logf(ssum);
        float dual = -eps * fmaf(LN2f, lse2, -LOGN);
        acc += ((ps < 2) ? 1.0 : -0.5) * (double)dual;
    }
    for (int off = 32; off; off >>= 1) acc += __shfl_xor(acc, off);
    __shared__ double red[4];
    int wave = tid >> 6, lane = tid & 63;
    if (lane == 0) red[wave] = acc;
    __syncthreads();
    if (tid == 0) out[0] = (float)((red[0] + red[1] + red[2] + red[3]) / (double)NPTS);
}

extern "C" void kernel_launch(void* const* d_in, const int* in_sizes, int n_in,
                              void* d_out, int out_size, void* d_ws, size_t ws_size,
                              hipStream_t stream) {
    const float* x = (const float*)d_in[0];
    const float* y = (const float*)d_in[1];
    float* ws = (float*)d_ws;
    float* out = (float*)d_out;

    prep_kernel<<<dim3((NPTS + 255) / 256), dim3(256), 0, stream>>>(x, y, ws);

    float eps_list[NSTEPS];
    for (int st = 0; st < NSTEPS; ++st)
        eps_list[st] = (st < 6) ? ldexpf(4.0f, -2 * st) : 0.0025f;

    for (int st = 0; st < NSTEPS; ++st) {
        float ep = eps_list[st];
        float ed0 = (st == 0) ? ep : eps_list[st - 1];
        sinkhorn_step<<<dim3(3 * BPP), dim3(256), 0, stream>>>(ws, ep, ed0, 0);
        sinkhorn_step<<<dim3(3 * BPP), dim3(256), 0, stream>>>(ws, ep, ep, 1);
    }

    finalize_kernel<<<dim3(1), dim3(256), 0, stream>>>(ws, out, eps_list[NSTEPS - 1]);
}

// Round 9
// 439.578 us; speedup vs baseline: 2.3906x; 2.3906x over previous
//
#include <hip/hip_runtime.h>
#include <math.h>

#define NPTS 4096
#define LOGN 8.317766166719343f   // log(4096)
#define LN2f 0.6931471805599453f
#define LOG2E 1.4426950408889634f

#define NSTEPS 11
#define JSPLIT 4
#define JCHUNK (NPTS / JSPLIT)            // 1024 columns per block
#define RPW 8                             // rows per wave
#define RPB 32                            // rows per block (4 waves)
#define NRBLK (NPTS / RPB)                // 128
#define BPP (NRBLK * JSPLIT)              // 512 blocks per problem; grid = 1536 (6/CU)

typedef float f2 __attribute__((ext_vector_type(2)));
static __device__ __forceinline__ f2 mk2(float a, float b) { f2 r; r.x = a; r.y = b; return r; }

// ws layout:
//   float2 pa[2*NPTS]   : (x,y)  per cloud (0=x-cloud, 1=y-cloud)
//   float2 pb[2*NPTS]   : (z,|p|^2) per cloud
//   float2 part[24*NPTS]: (m,s) partial; index ((prob*2+side)*JSPLIT + js)*NPTS + row
#define PA_F2(ws)   ((float2*)(ws))
#define PB_F2(ws)   ((float2*)((ws) + 4 * NPTS))
#define PART_F2(ws) ((float2*)((ws) + 8 * NPTS))

__global__ void prep_kernel(const float* __restrict__ x, const float* __restrict__ y,
                            float* __restrict__ ws) {
    int j = blockIdx.x * 256 + threadIdx.x;
    if (j >= NPTS) return;
    float2* pa = PA_F2(ws); float2* pb = PB_F2(ws); float2* part = PART_F2(ws);
    float ax = x[3*j], ay = x[3*j+1], az = x[3*j+2];
    pa[j] = make_float2(ax, ay);
    pb[j] = make_float2(az, ax*ax + ay*ay + az*az);
    float bx = y[3*j], by = y[3*j+1], bz = y[3*j+2];
    pa[NPTS + j] = make_float2(bx, by);
    pb[NPTS + j] = make_float2(bz, bx*bx + by*by + bz*bz);
    // init partials so decoded dual == 0 at any eps: lse2 = 12 = log2(4096)
    #pragma unroll
    for (int ps = 0; ps < 6; ++ps) {
        #pragma unroll
        for (int p = 0; p < JSPLIT; ++p)
            part[(ps*JSPLIT + p) * NPTS + j] =
                (p == 0) ? make_float2(12.0f, 1.0f) : make_float2(0.0f, 0.0f);
    }
}

// One Sinkhorn half-update, online chunked-max, hw exp2 (R4 inner loop).
// launch_bounds(256,4): VGPR cap 128 — R8's (256,6) cap of 85 caused scratch
// spill (39+69 MB/dispatch HBM traffic). Actual VGPR ~80 -> 6 waves/SIMD.
__global__ void __launch_bounds__(256, 4) sinkhorn_step(float* __restrict__ ws,
        float eps, float eps_dec, int half) {
    const float2* pa = PA_F2(ws);
    const float2* pb = PB_F2(ws);
    float2* part = PART_F2(ws);

    int bid = blockIdx.x;
    int prob = bid / BPP;                 // 0: xy, 1: xx, 2: yy
    int rem  = bid % BPP;
    int js   = rem & (JSPLIT - 1);
    int rblk = rem / JSPLIT;

    int rc, cc, in_side, out_side;
    if (half == 0) { rc = (prob == 2) ? 1 : 0; cc = (prob == 1) ? 0 : 1; in_side = 1; out_side = 0; }
    else           { rc = (prob == 1) ? 0 : 1; cc = (prob == 2) ? 1 : 0; in_side = 0; out_side = 1; }

    const float k = LOG2E / eps;          // base-2 log scale
    const float nhk = -0.5f * k;
    const int jbase = js * JCHUNK;

    __shared__ float bxL[JCHUNK], byL[JCHUNK], bzL[JCHUNK], uL[JCHUNK];  // 16 KB

    // ---- stage cols + decode input duals (4-way partial merge) ----
    {
        const float2* part_in = part + (prob*2 + in_side) * JSPLIT * NPTS;
        for (int i = threadIdx.x; i < JCHUNK; i += 256) {
            int j = jbase + i;
            float2 P0 = part_in[j];
            float2 P1 = part_in[NPTS + j];
            float2 P2 = part_in[2*NPTS + j];
            float2 P3 = part_in[3*NPTS + j];
            float M = fmaxf(fmaxf(P0.x, P1.x), fmaxf(P2.x, P3.x));
            float ssum = P0.y * __builtin_amdgcn_exp2f(P0.x - M)
                       + P1.y * __builtin_amdgcn_exp2f(P1.x - M)
                       + P2.y * __builtin_amdgcn_exp2f(P2.x - M)
                       + P3.y * __builtin_amdgcn_exp2f(P3.x - M);
            float lse2 = M + __builtin_amdgcn_logf(ssum);
            float g = -eps_dec * fmaf(LN2f, lse2, -LOGN);
            float2 A = pa[cc*NPTS + j];
            float2 B = pb[cc*NPTS + j];
            bxL[i] = A.x; byL[i] = A.y; bzL[i] = B.x;
            uL[i] = fmaf(B.y, nhk, g * k);
        }
    }
    __syncthreads();

    int wave = threadIdx.x >> 6;
    int lane = threadIdx.x & 63;
    int r0 = rblk * RPB + wave * RPW;

    float2* part_out = part + ((prob*2 + out_side) * JSPLIT + js) * NPTS;

    f2 AX[RPW], AY[RPW], AZ[RPW];
    float rak[RPW], m[RPW], s[RPW];
    #pragma unroll
    for (int r = 0; r < RPW; ++r) {
        float2 RA = pa[rc*NPTS + r0 + r];
        float2 RB = pb[rc*NPTS + r0 + r];
        float ax = RA.x * k, ay = RA.y * k, az = RB.x * k;
        AX[r] = mk2(ax, ax); AY[r] = mk2(ay, ay); AZ[r] = mk2(az, az);
        rak[r] = nhk * RB.y;
        m[r] = -INFINITY; s[r] = 0.0f;
    }

    // ---- main loop: 8 j's/lane/superiter (4 adjacent pairs), chunk max, 1 rescale ----
    for (int su = 0; su < JCHUNK / 512; ++su) {   // 2 superiters
        int c0 = su * 512 + 2 * lane;
        f2 BX[4], BY[4], BZ[4], U[4];
        #pragma unroll
        for (int p = 0; p < 4; ++p) {
            int j0 = c0 + p * 128;
            BX[p] = *(const f2*)&bxL[j0];
            BY[p] = *(const f2*)&byL[j0];
            BZ[p] = *(const f2*)&bzL[j0];
            U[p]  = *(const f2*)&uL[j0];
        }
        #pragma unroll
        for (int r = 0; r < RPW; ++r) {
            f2 t0 = __builtin_elementwise_fma(AX[r], BX[0],
                     __builtin_elementwise_fma(AY[r], BY[0],
                      __builtin_elementwise_fma(AZ[r], BZ[0], U[0])));
            f2 t1 = __builtin_elementwise_fma(AX[r], BX[1],
                     __builtin_elementwise_fma(AY[r], BY[1],
                      __builtin_elementwise_fma(AZ[r], BZ[1], U[1])));
            f2 t2 = __builtin_elementwise_fma(AX[r], BX[2],
                     __builtin_elementwise_fma(AY[r], BY[2],
                      __builtin_elementwise_fma(AZ[r], BZ[2], U[2])));
            f2 t3 = __builtin_elementwise_fma(AX[r], BX[3],
                     __builtin_elementwise_fma(AY[r], BY[3],
                      __builtin_elementwise_fma(AZ[r], BZ[3], U[3])));
            f2 q = __builtin_elementwise_max(
                     __builtin_elementwise_max(t0, t1),
                     __builtin_elementwise_max(t2, t3));
            float mn = fmaxf(fmaxf(q.x, q.y), m[r]);       // v_max3
            float er = __builtin_amdgcn_exp2f(m[r] - mn);  // 1 rescale per chunk of 8
            f2 mn2 = mk2(mn, mn);
            f2 d0 = t0 - mn2, d1 = t1 - mn2, d2 = t2 - mn2, d3 = t3 - mn2;
            f2 e0, e1, e2, e3;
            e0.x = __builtin_amdgcn_exp2f(d0.x); e0.y = __builtin_amdgcn_exp2f(d0.y);
            e1.x = __builtin_amdgcn_exp2f(d1.x); e1.y = __builtin_amdgcn_exp2f(d1.y);
            e2.x = __builtin_amdgcn_exp2f(d2.x); e2.y = __builtin_amdgcn_exp2f(d2.y);
            e3.x = __builtin_amdgcn_exp2f(d3.x); e3.y = __builtin_amdgcn_exp2f(d3.y);
            f2 acc = (e0 + e1) + (e2 + e3);
            s[r] = fmaf(s[r], er, acc.x + acc.y);
            m[r] = mn;
        }
    }

    // ---- wave reduce: max butterfly, one rescale, sum butterfly; write partial ----
    #pragma unroll
    for (int r = 0; r < RPW; ++r) {
        float M = m[r];
        for (int off = 32; off; off >>= 1) M = fmaxf(M, __shfl_xor(M, off));
        float ss = s[r] * __builtin_amdgcn_exp2f(m[r] - M);
        for (int off = 32; off; off >>= 1) ss += __shfl_xor(ss, off);
        if (lane == 0) part_out[r0 + r] = make_float2(M + rak[r], ss);
    }
}

__global__ void finalize_kernel(const float* __restrict__ ws, float* __restrict__ out,
                                float eps) {
    const float2* part = PART_F2((float*)ws);
    int tid = threadIdx.x;
    double acc = 0.0;
    for (int idx = tid; idx < 6 * NPTS; idx += 256) {
        int ps = idx >> 12;            // prob*2+side
        int row = idx & (NPTS - 1);
        const float2* pb_ = part + ps * JSPLIT * NPTS + row;
        float2 P0 = pb_[0];
        float2 P1 = pb_[NPTS];
        float2 P2 = pb_[2*NPTS];
        float2 P3 = pb_[3*NPTS];
        float M = fmaxf(fmaxf(P0.x, P1.x), fmaxf(P2.x, P3.x));
        float ssum = P0.y * __builtin_amdgcn_exp2f(P0.x - M)
                   + P1.y * __builtin_amdgcn_exp2f(P1.x - M)
                   + P2.y * __builtin_amdgcn_exp2f(P2.x - M)
                   + P3.y * __builtin_amdgcn_exp2f(P3.x - M);
        float lse2 = M + __builtin_amdgcn_logf(ssum);
        float dual = -eps * fmaf(LN2f, lse2, -LOGN);
        acc += ((ps < 2) ? 1.0 : -0.5) * (double)dual;
    }
    for (int off = 32; off; off >>= 1) acc += __shfl_xor(acc, off);
    __shared__ double red[4];
    int wave = tid >> 6, lane = tid & 63;
    if (lane == 0) red[wave] = acc;
    __syncthreads();
    if (tid == 0) out[0] = (float)((red[0] + red[1] + red[2] + red[3]) / (double)NPTS);
}

extern "C" void kernel_launch(void* const* d_in, const int* in_sizes, int n_in,
                              void* d_out, int out_size, void* d_ws, size_t ws_size,
                              hipStream_t stream) {
    const float* x = (const float*)d_in[0];
    const float* y = (const float*)d_in[1];
    float* ws = (float*)d_ws;
    float* out = (float*)d_out;

    prep_kernel<<<dim3((NPTS + 255) / 256), dim3(256), 0, stream>>>(x, y, ws);

    float eps_list[NSTEPS];
    for (int st = 0; st < NSTEPS; ++st)
        eps_list[st] = (st < 6) ? ldexpf(4.0f, -2 * st) : 0.0025f;

    for (int st = 0; st < NSTEPS; ++st) {
        float ep = eps_list[st];
        float ed0 = (st == 0) ? ep : eps_list[st - 1];
        sinkhorn_step<<<dim3(3 * BPP), dim3(256), 0, stream>>>(ws, ep, ed0, 0);
        sinkhorn_step<<<dim3(3 * BPP), dim3(256), 0, stream>>>(ws, ep, ep, 1);
    }

    finalize_kernel<<<dim3(1), dim3(256), 0, stream>>>(ws, out, eps_list[NSTEPS - 1]);
}